// Round 10
// baseline (187.654 us; speedup 1.0000x reference)
//
#include <hip/hip_runtime.h>
#include <math.h>

#define WF 64

__device__ __forceinline__ float silu_f(float v){ return v / (1.0f + expf(-v)); }

// ---------- CSR build ----------
__global__ __launch_bounds__(256) void k_count(const int* __restrict__ dst, int* __restrict__ cnt, int E){
  int e = blockIdx.x*blockDim.x + threadIdx.x;
  if (e < E) atomicAdd(&cnt[dst[e]], 1);
}

// block-local exclusive scan over chunks of 2048 (256 thr x 8 items)
__global__ __launch_bounds__(256) void k_scan1(const int* __restrict__ cnt, int* __restrict__ rowstart, int* __restrict__ bsum, int N){
  __shared__ int s[256];
  int tid = threadIdx.x;
  int base = blockIdx.x*2048 + tid*8;
  int loc[8]; int tsum = 0;
#pragma unroll
  for (int j=0;j<8;++j){ int idx=base+j; int v = (idx<N)?cnt[idx]:0; loc[j]=tsum; tsum+=v; }
  s[tid]=tsum; __syncthreads();
  for (int off=1; off<256; off<<=1){
    int v = (tid>=off)? s[tid-off] : 0;
    __syncthreads();
    s[tid] += v;
    __syncthreads();
  }
  int texc = s[tid] - tsum;
  if (tid==255) bsum[blockIdx.x] = s[255];
#pragma unroll
  for (int j=0;j<8;++j){ int idx=base+j; if (idx<N) rowstart[idx] = texc + loc[j]; }
}

// scan3: adds block prefix (from bsum), writes cursor/dinv and dxp = {di, di*x}
__global__ __launch_bounds__(256) void k_scan3(const int* __restrict__ bsum, const int* __restrict__ cnt,
                        const float* __restrict__ x,
                        int* __restrict__ rowstart, int* __restrict__ cursor,
                        float* __restrict__ dinv, float4* __restrict__ dxp,
                        int N, int E, int nb){
  __shared__ int boffs;
  int tid = threadIdx.x;
  int b = (blockIdx.x*blockDim.x) >> 11;   // uniform within block (256 <= 2048)
  if (tid < WF){
    int v = (tid < nb && tid < b) ? bsum[tid] : 0;
#pragma unroll
    for (int off=32; off; off>>=1) v += __shfl_down(v, off);
    if (tid==0) boffs = v;
  }
  __syncthreads();
  int idx = blockIdx.x*blockDim.x + tid;
  if (idx < N){
    int v = rowstart[idx] + boffs;
    rowstart[idx]=v; cursor[idx]=v;
    float di = rsqrtf((float)(cnt[idx]+1));   // +1 self-loop
    dinv[idx] = di;
    float4 o;
    o.x = di;
    o.y = di*x[3*idx+0];
    o.z = di*x[3*idx+1];
    o.w = di*x[3*idx+2];
    dxp[idx] = o;
  }
  if (idx==0) rowstart[N]=E;
}

// fill CSR: minimum scatter — one 4B colsrc write + cursor atomic per edge
__global__ __launch_bounds__(256) void k_fill(const int* __restrict__ src, const int* __restrict__ dst,
                       int* __restrict__ cursor, int* __restrict__ colsrc, int E){
  int e = blockIdx.x*blockDim.x + threadIdx.x;
  if (e < E){
    int d = dst[e];
    int pos = atomicAdd(&cursor[d], 1);
    colsrc[pos] = src[e];
  }
}

// ---------- layer 1: CSR walk over dxp (16B gathers, 4x unroll), then @W1+b1, silu ----------
__global__ __launch_bounds__(256) void k_l1(const float4* __restrict__ dxp,
                     const int* __restrict__ rowstart, const int* __restrict__ colsrc,
                     const float* __restrict__ W1, const float* __restrict__ b1,
                     float* __restrict__ h1s, int N){
  __shared__ float w[300];
  __shared__ float bb[100];
  int tid = threadIdx.x;
  for (int t=tid; t<300; t+=blockDim.x) w[t]=W1[t];
  for (int t=tid; t<100; t+=blockDim.x) bb[t]=b1[t];
  __syncthreads();
  int i = blockIdx.x*blockDim.x + tid;
  if (i >= N) return;
  float4 self = dxp[i];
  float di = self.x;
  float sx = self.y, sy = self.z, sz = self.w;
  int jb = rowstart[i], je = rowstart[i+1];
  int j = jb;
  for (; j+3 < je; j += 4){
    float4 r0 = dxp[colsrc[j]];
    float4 r1 = dxp[colsrc[j+1]];
    float4 r2 = dxp[colsrc[j+2]];
    float4 r3 = dxp[colsrc[j+3]];
    sx += (r0.y + r1.y) + (r2.y + r3.y);
    sy += (r0.z + r1.z) + (r2.z + r3.z);
    sz += (r0.w + r1.w) + (r2.w + r3.w);
  }
  for (; j < je; ++j){
    float4 r = dxp[colsrc[j]];
    sx += r.y; sy += r.z; sz += r.w;
  }
  sx*=di; sy*=di; sz*=di;
  float* orow = h1s + (size_t)i*100;
#pragma unroll
  for (int f0=0; f0<100; f0+=4){
    float4 o;
    o.x = silu_f(sx*w[f0+0] + sy*w[100+f0+0] + sz*w[200+f0+0] + bb[f0+0]);
    o.y = silu_f(sx*w[f0+1] + sy*w[100+f0+1] + sz*w[200+f0+1] + bb[f0+1]);
    o.z = silu_f(sx*w[f0+2] + sy*w[100+f0+2] + sz*w[200+f0+2] + bb[f0+2]);
    o.w = silu_f(sx*w[f0+3] + sy*w[100+f0+3] + sz*w[200+f0+3] + bb[f0+3]);
    *(float4*)&orow[f0] = o;
  }
}

// ---------- layer 2 aggregation: a2 = A_norm h1s  (100 feats) ----------
// one WAVE per node; lanes 0..49 own 2 feats (float2); weight = dinv[u] broadcast
__global__ __launch_bounds__(256) void k_agg2(const float* __restrict__ h1s, const int* __restrict__ rowstart,
                       const int* __restrict__ colsrc, const float* __restrict__ dinv,
                       float* __restrict__ a2, int N){
  int node = blockIdx.x*4 + (threadIdx.x >> 6);
  int lane = threadIdx.x & 63;
  if (node >= N || lane >= 50) return;
  float di = dinv[node];
  const float* selfrow = h1s + (size_t)node*100 + 2*lane;
  float2 v = *(const float2*)selfrow;
  float ax = di*v.x, ay = di*v.y;
  int jb = rowstart[node], je = rowstart[node+1];
  int j = jb;
  for (; j+1 < je; j += 2){
    int u0 = colsrc[j];   float w0 = dinv[u0];
    int u1 = colsrc[j+1]; float w1 = dinv[u1];
    float2 r0 = *(const float2*)(h1s + (size_t)u0*100 + 2*lane);
    float2 r1 = *(const float2*)(h1s + (size_t)u1*100 + 2*lane);
    ax += w0*r0.x; ay += w0*r0.y;
    ax += w1*r1.x; ay += w1*r1.y;
  }
  if (j < je){
    int u = colsrc[j]; float wv = dinv[u];
    float2 r = *(const float2*)(h1s + (size_t)u*100 + 2*lane);
    ax += wv*r.x; ay += wv*r.y;
  }
  float2 o; o.x = di*ax; o.y = di*ay;
  *(float2*)(a2 + (size_t)node*100 + 2*lane) = o;
}

// ---------- layer 2 matmul + fused mean-pool accumulation ----------
// grid (ceil(N/128), 5). block 128 (2 waves) — hipcc grants ~144 VGPR to
// 128-thr blocks (R7 evidence), so the 2-stage register pipeline survives.
// tile 128n x 40f, micro 4n x 10f (R5-proven conflict-free LDS patterns).
// Epilogue: silu -> LDS pooled accumulation (8-graph window) -> few atomics.
#define CH 20
__global__ __launch_bounds__(128) void k_mm2(const float* __restrict__ a2, const float* __restrict__ W2,
                      const float* __restrict__ b2, const int* __restrict__ batch,
                      float* __restrict__ pooled, int N){
  __shared__ float aS[CH][132];   // aS[kl][n]; reused as pooled scratch in epilogue
  __shared__ float wS[100][48];   // wS[k][g*12 + j], j<10
  int tid = threadIdx.x;
  int fg = tid & 3;     // 4 f-groups x 10
  int ng = tid >> 2;    // 32 node-groups x 4 consecutive nodes
  int n0 = blockIdx.x * 128;
  int fb = blockIdx.y;  // f-tile base fb*40

  // stage W tile once: 100k x 40f
  for (int idx = tid; idx < 4000; idx += 128){
    int k = idx / 40, f = idx - k*40;
    int g = f / 10, j = f - g*10;
    wS[k][g*12 + j] = W2[(size_t)k*200 + fb*40 + f];
  }

  float acc[4][10];
#pragma unroll
  for (int i=0;i<4;++i)
#pragma unroll
    for (int j=0;j<10;++j) acc[i][j]=0.f;

  for (int kc = 0; kc < 5; ++kc){
    int kt = kc*CH;
    __syncthreads();   // kc=0: wS staged; else: aS readers done
    // stage A chunk transposed: a2[n0+n][kt+q*4..+3] -> aS[q*4+r][n]
#pragma unroll
    for (int c = 0; c < 5; ++c){
      int idx = c*128 + tid;            // [0,640)
      int n = idx / 5, q = idx - n*5;   // n<128, q<5
      int gn = n0 + n;
      float4 v = make_float4(0.f,0.f,0.f,0.f);
      if (gn < N) v = *(const float4*)(a2 + (size_t)gn*100 + kt + q*4);
      aS[q*4+0][n] = v.x;
      aS[q*4+1][n] = v.y;
      aS[q*4+2][n] = v.z;
      aS[q*4+3][n] = v.w;
    }
    __syncthreads();
    // explicit 2-stage register pipeline over kl
    float a0[4], w0[10];
    *(float4*)a0 = *(const float4*)&aS[0][ng*4];
    {
      const float* wr = &wS[kt][fg*12];
      *(float4*)&w0[0] = *(const float4*)&wr[0];
      *(float4*)&w0[4] = *(const float4*)&wr[4];
      *(float2*)&w0[8] = *(const float2*)&wr[8];
    }
#pragma unroll
    for (int kl = 0; kl < CH; ++kl){
      float a1r[4], w1r[10];
      if (kl+1 < CH){
        *(float4*)a1r = *(const float4*)&aS[kl+1][ng*4];
        const float* wr = &wS[kt+kl+1][fg*12];
        *(float4*)&w1r[0] = *(const float4*)&wr[0];
        *(float4*)&w1r[4] = *(const float4*)&wr[4];
        *(float2*)&w1r[8] = *(const float2*)&wr[8];
      }
#pragma unroll
      for (int j=0;j<10;++j){
        float wv = w0[j];
#pragma unroll
        for (int i=0;i<4;++i) acc[i][j] += a0[i]*wv;
      }
      if (kl+1 < CH){
#pragma unroll
        for (int i=0;i<4;++i) a0[i] = a1r[i];
#pragma unroll
        for (int j=0;j<10;++j) w0[j] = w1r[j];
      }
    }
  }

  // ---- epilogue: silu + per-block LDS pooled accumulation ----
  float* plL = &aS[0][0];          // 8 graphs x 40 f = 320 floats (aS reused)
  __syncthreads();                 // all aS readers done
  for (int idx = tid; idx < 320; idx += 128) plL[idx] = 0.f;
  __syncthreads();

  int fbase = fb*40 + fg*10;
  float bias[10];
#pragma unroll
  for (int j=0;j<10;++j) bias[j] = b2[fbase+j];
  int g0 = batch[n0];              // n0 < N for all blocks in grid
  float s[10];
  int gprev = -1;
#pragma unroll
  for (int i=0;i<4;++i){
    int n = n0 + ng*4 + i;
    if (n < N){
      int g = batch[n];
      if (g != gprev){
        if (gprev >= 0){
          int dg = gprev - g0;
          if (dg < 8){
#pragma unroll
            for (int j=0;j<10;++j) atomicAdd(&plL[dg*40 + fg*10 + j], s[j]);
          } else {
#pragma unroll
            for (int j=0;j<10;++j) atomicAdd(&pooled[(size_t)gprev*200 + fbase + j], s[j]);
          }
        }
        gprev = g;
#pragma unroll
        for (int j=0;j<10;++j) s[j] = 0.f;
      }
#pragma unroll
      for (int j=0;j<10;++j) s[j] += silu_f(acc[i][j] + bias[j]);
    }
  }
  if (gprev >= 0){
    int dg = gprev - g0;
    if (dg < 8){
#pragma unroll
      for (int j=0;j<10;++j) atomicAdd(&plL[dg*40 + fg*10 + j], s[j]);
    } else {
#pragma unroll
      for (int j=0;j<10;++j) atomicAdd(&pooled[(size_t)gprev*200 + fbase + j], s[j]);
    }
  }
  __syncthreads();
  for (int idx = tid; idx < 320; idx += 128){
    float v = plL[idx];
    if (v != 0.f){
      int r = idx / 40, f = idx - r*40;
      atomicAdd(&pooled[(size_t)(g0+r)*200 + fb*40 + f], v);
    }
  }
}

// ---------- head: mean finalize + MLP, one block per graph ----------
__global__ __launch_bounds__(256) void k_head(const float* __restrict__ pooled, const int* __restrict__ batch,
                       const float* __restrict__ W3, const float* __restrict__ b3,
                       const float* __restrict__ W4, const float* __restrict__ b4,
                       float* __restrict__ out, int N){
  __shared__ float pl[200];
  __shared__ float h3[100];
  int g = blockIdx.x; int tid = threadIdx.x;
  // lower_bound(batch, g) and lower_bound(batch, g+1) to get node count
  int lo=0, hi=N;
  while (lo<hi){ int m=(lo+hi)>>1; if (batch[m] < g) lo=m+1; else hi=m; }
  int s = lo;
  hi=N;
  while (lo<hi){ int m=(lo+hi)>>1; if (batch[m] < g+1) lo=m+1; else hi=m; }
  int e = lo;
  float inv = (e>s) ? 1.0f/(float)(e-s) : 0.0f;
  if (tid < 200) pl[tid] = pooled[(size_t)g*200 + tid] * inv;
  __syncthreads();
  if (tid < 100){
    float acc = b3[tid];
    for (int k=0;k<200;++k) acc += pl[k]*W3[k*100+tid];
    h3[tid] = silu_f(acc);
  }
  __syncthreads();
  if (tid < WF){
    float p = 0.f;
    if (tid < 100)      p  = h3[tid]     * W4[tid];
    if (tid + 64 < 100) p += h3[tid+64]  * W4[tid+64];
#pragma unroll
    for (int off=32; off; off>>=1) p += __shfl_down(p, off);
    if (tid==0) out[g] = p + b4[0];
  }
}

extern "C" void kernel_launch(void* const* d_in, const int* in_sizes, int n_in,
                              void* d_out, int out_size, void* d_ws, size_t ws_size,
                              hipStream_t stream){
  const float* x  = (const float*)d_in[0];
  const int*   ei = (const int*)  d_in[1];
  const int* batch= (const int*)  d_in[2];
  const float* W1 = (const float*)d_in[4];
  const float* b1 = (const float*)d_in[5];
  const float* W2 = (const float*)d_in[6];
  const float* b2 = (const float*)d_in[7];
  const float* W3 = (const float*)d_in[8];
  const float* b3 = (const float*)d_in[9];
  const float* W4 = (const float*)d_in[10];
  const float* b4 = (const float*)d_in[11];
  float* out = (float*)d_out;

  int N = in_sizes[0]/3;
  int E = in_sizes[1]/2;
  int G = out_size;
  const int* src = ei;
  const int* dst = ei + E;

  char* base = (char*)d_ws; size_t off = 0;
  auto alloc = [&](size_t bytes)->void*{
    void* p = base + off;
    off = (off + bytes + 255) & ~(size_t)255;
    return p;
  };
  // zero-init group first (single memset): cnt, pooled
  int*   cnt      = (int*)  alloc((size_t)N*4);
  float* pooled   = (float*)alloc((size_t)G*200*4);
  size_t zbytes   = off;
  int*   rowstart = (int*)  alloc((size_t)(N+1)*4);
  int*   cursor   = (int*)  alloc((size_t)N*4);
  int*   bsum     = (int*)  alloc(4096);
  int*   colsrc   = (int*)  alloc((size_t)E*4);
  float* dinv     = (float*)alloc((size_t)N*4);
  float4* dxp     = (float4*)alloc((size_t)N*16);
  float* h1s      = (float*)alloc((size_t)N*100*4);
  float* a2       = (float*)alloc((size_t)N*100*4);
  (void)ws_size; (void)n_in;

  hipMemsetAsync(base, 0, zbytes, stream);
  int gE = (E+255)/256;
  k_count<<<gE,256,0,stream>>>(dst, cnt, E);
  int nb = (N+2047)/2048;
  k_scan1<<<nb,256,0,stream>>>(cnt, rowstart, bsum, N);
  k_scan3<<<(N+255)/256,256,0,stream>>>(bsum, cnt, x, rowstart, cursor, dinv, dxp, N, E, nb);
  k_fill<<<gE,256,0,stream>>>(src, dst, cursor, colsrc, E);
  k_l1<<<(N+255)/256,256,0,stream>>>(dxp, rowstart, colsrc, W1, b1, h1s, N);
  k_agg2<<<(N+3)/4,256,0,stream>>>(h1s, rowstart, colsrc, dinv, a2, N);
  dim3 gmm((N+127)/128, 5);
  k_mm2<<<gmm,128,0,stream>>>(a2, W2, b2, batch, pooled, N);
  k_head<<<G,256,0,stream>>>(pooled, batch, W3, b3, W4, b4, out, N);
}

// Round 11
// 184.200 us; speedup vs baseline: 1.0188x; 1.0188x over previous
//
#include <hip/hip_runtime.h>
#include <math.h>

#define WF 64

__device__ __forceinline__ float silu_f(float v){ return v / (1.0f + expf(-v)); }

// ---------- CSR build ----------
__global__ __launch_bounds__(256) void k_count(const int* __restrict__ dst, int* __restrict__ cnt, int E){
  int e = blockIdx.x*blockDim.x + threadIdx.x;
  if (e < E) atomicAdd(&cnt[dst[e]], 1);
}

// block-local exclusive scan over chunks of 2048 (256 thr x 8 items)
__global__ __launch_bounds__(256) void k_scan1(const int* __restrict__ cnt, int* __restrict__ rowstart, int* __restrict__ bsum, int N){
  __shared__ int s[256];
  int tid = threadIdx.x;
  int base = blockIdx.x*2048 + tid*8;
  int loc[8]; int tsum = 0;
#pragma unroll
  for (int j=0;j<8;++j){ int idx=base+j; int v = (idx<N)?cnt[idx]:0; loc[j]=tsum; tsum+=v; }
  s[tid]=tsum; __syncthreads();
  for (int off=1; off<256; off<<=1){
    int v = (tid>=off)? s[tid-off] : 0;
    __syncthreads();
    s[tid] += v;
    __syncthreads();
  }
  int texc = s[tid] - tsum;
  if (tid==255) bsum[blockIdx.x] = s[255];
#pragma unroll
  for (int j=0;j<8;++j){ int idx=base+j; if (idx<N) rowstart[idx] = texc + loc[j]; }
}

// scan3: adds block prefix (from bsum), writes cursor/dinv and dxp = {di, di*x}
__global__ __launch_bounds__(256) void k_scan3(const int* __restrict__ bsum, const int* __restrict__ cnt,
                        const float* __restrict__ x,
                        int* __restrict__ rowstart, int* __restrict__ cursor,
                        float* __restrict__ dinv, float4* __restrict__ dxp,
                        int N, int E, int nb){
  __shared__ int boffs;
  int tid = threadIdx.x;
  int b = (blockIdx.x*blockDim.x) >> 11;   // uniform within block (256 <= 2048)
  if (tid < WF){
    int v = (tid < nb && tid < b) ? bsum[tid] : 0;
#pragma unroll
    for (int off=32; off; off>>=1) v += __shfl_down(v, off);
    if (tid==0) boffs = v;
  }
  __syncthreads();
  int idx = blockIdx.x*blockDim.x + tid;
  if (idx < N){
    int v = rowstart[idx] + boffs;
    rowstart[idx]=v; cursor[idx]=v;
    float di = rsqrtf((float)(cnt[idx]+1));   // +1 self-loop
    dinv[idx] = di;
    float4 o;
    o.x = di;
    o.y = di*x[3*idx+0];
    o.z = di*x[3*idx+1];
    o.w = di*x[3*idx+2];
    dxp[idx] = o;
  }
  if (idx==0) rowstart[N]=E;
}

// fill CSR: minimum scatter — one 4B colsrc write + cursor atomic per edge
__global__ __launch_bounds__(256) void k_fill(const int* __restrict__ src, const int* __restrict__ dst,
                       int* __restrict__ cursor, int* __restrict__ colsrc, int E){
  int e = blockIdx.x*blockDim.x + threadIdx.x;
  if (e < E){
    int d = dst[e];
    int pos = atomicAdd(&cursor[d], 1);
    colsrc[pos] = src[e];
  }
}

// ---------- layer 1: CSR walk over dxp (16B gathers, 4x unroll), then @W1+b1, silu ----------
__global__ __launch_bounds__(256) void k_l1(const float4* __restrict__ dxp,
                     const int* __restrict__ rowstart, const int* __restrict__ colsrc,
                     const float* __restrict__ W1, const float* __restrict__ b1,
                     float* __restrict__ h1s, int N){
  __shared__ float w[300];
  __shared__ float bb[100];
  int tid = threadIdx.x;
  for (int t=tid; t<300; t+=blockDim.x) w[t]=W1[t];
  for (int t=tid; t<100; t+=blockDim.x) bb[t]=b1[t];
  __syncthreads();
  int i = blockIdx.x*blockDim.x + tid;
  if (i >= N) return;
  float4 self = dxp[i];
  float di = self.x;
  float sx = self.y, sy = self.z, sz = self.w;
  int jb = rowstart[i], je = rowstart[i+1];
  int j = jb;
  for (; j+3 < je; j += 4){
    float4 r0 = dxp[colsrc[j]];
    float4 r1 = dxp[colsrc[j+1]];
    float4 r2 = dxp[colsrc[j+2]];
    float4 r3 = dxp[colsrc[j+3]];
    sx += (r0.y + r1.y) + (r2.y + r3.y);
    sy += (r0.z + r1.z) + (r2.z + r3.z);
    sz += (r0.w + r1.w) + (r2.w + r3.w);
  }
  for (; j < je; ++j){
    float4 r = dxp[colsrc[j]];
    sx += r.y; sy += r.z; sz += r.w;
  }
  sx*=di; sy*=di; sz*=di;
  float* orow = h1s + (size_t)i*100;
#pragma unroll
  for (int f0=0; f0<100; f0+=4){
    float4 o;
    o.x = silu_f(sx*w[f0+0] + sy*w[100+f0+0] + sz*w[200+f0+0] + bb[f0+0]);
    o.y = silu_f(sx*w[f0+1] + sy*w[100+f0+1] + sz*w[200+f0+1] + bb[f0+1]);
    o.z = silu_f(sx*w[f0+2] + sy*w[100+f0+2] + sz*w[200+f0+2] + bb[f0+2]);
    o.w = silu_f(sx*w[f0+3] + sy*w[100+f0+3] + sz*w[200+f0+3] + bb[f0+3]);
    *(float4*)&orow[f0] = o;
  }
}

// ---------- layer 2 aggregation: a2 = A_norm h1s  (100 feats) ----------
// HALF-WAVE per node: 32-lane group, lanes 0..24 own 4 feats via one float4
// gather (400B = exact row) per neighbor. 8 nodes per 256-thr block.
__global__ __launch_bounds__(256) void k_agg2(const float* __restrict__ h1s, const int* __restrict__ rowstart,
                       const int* __restrict__ colsrc, const float* __restrict__ dinv,
                       float* __restrict__ a2, int N){
  int node = blockIdx.x*8 + (threadIdx.x >> 5);
  int lane = threadIdx.x & 31;
  if (node >= N) return;
  bool act = lane < 25;
  float di = dinv[node];
  float4 acc = make_float4(0.f,0.f,0.f,0.f);
  if (act){
    float4 v = *(const float4*)(h1s + (size_t)node*100 + lane*4);
    acc.x = di*v.x; acc.y = di*v.y; acc.z = di*v.z; acc.w = di*v.w;
  }
  int jb = rowstart[node], je = rowstart[node+1];
  int j = jb;
  for (; j+1 < je; j += 2){
    int u0 = colsrc[j];   float w0 = dinv[u0];
    int u1 = colsrc[j+1]; float w1 = dinv[u1];
    if (act){
      float4 r0 = *(const float4*)(h1s + (size_t)u0*100 + lane*4);
      float4 r1 = *(const float4*)(h1s + (size_t)u1*100 + lane*4);
      acc.x += w0*r0.x + w1*r1.x;
      acc.y += w0*r0.y + w1*r1.y;
      acc.z += w0*r0.z + w1*r1.z;
      acc.w += w0*r0.w + w1*r1.w;
    }
  }
  if (j < je){
    int u = colsrc[j]; float wv = dinv[u];
    if (act){
      float4 r = *(const float4*)(h1s + (size_t)u*100 + lane*4);
      acc.x += wv*r.x; acc.y += wv*r.y; acc.z += wv*r.z; acc.w += wv*r.w;
    }
  }
  if (act){
    float4 o;
    o.x = di*acc.x; o.y = di*acc.y; o.z = di*acc.z; o.w = di*acc.w;
    *(float4*)(a2 + (size_t)node*100 + lane*4) = o;
  }
}

// ---------- layer 2 matmul + fused mean-pool accumulation ----------
// R5-proven geometry: grid (ceil(N/256), 5), block 256 (4 waves),
// tile 256n x 40f, micro 4n x 10f, SIMPLE inner loop (compiler schedules).
// NEW: conflict-free A staging (uniform row per ds_write, stride-1 cols).
// Epilogue: silu -> LDS pooled accumulation (16-graph window) -> few atomics.
#define CH 20
__global__ __launch_bounds__(256, 2) void k_mm2(const float* __restrict__ a2, const float* __restrict__ W2,
                      const float* __restrict__ b2, const int* __restrict__ batch,
                      float* __restrict__ pooled, int N){
  __shared__ float aS[CH][260];   // aS[kl][n]; reused as pooled scratch in epilogue
  __shared__ float wS[100][48];   // wS[k][g*12 + j], j<10
  int tid = threadIdx.x;
  int fg = tid & 3;     // 4 f-groups x 10
  int ng = tid >> 2;    // 64 node-groups x 4 consecutive nodes
  int n0 = blockIdx.x * 256;
  int fb = blockIdx.y;  // f-tile base fb*40

  // stage W tile once: 100k x 40f
  for (int idx = tid; idx < 4000; idx += 256){
    int k = idx / 40, f = idx - k*40;
    int g = f / 10, j = f - g*10;
    wS[k][g*12 + j] = W2[(size_t)k*200 + fb*40 + f];
  }

  float acc[4][10];
#pragma unroll
  for (int i=0;i<4;++i)
#pragma unroll
    for (int j=0;j<10;++j) acc[i][j]=0.f;

  int gn = n0 + tid;
  bool inb = (gn < N);
  const float* arow = a2 + (size_t)gn*100;

  for (int kc = 0; kc < 5; ++kc){
    int kt = kc*CH;
    __syncthreads();   // kc=0: wS staged; else: aS readers done
    // stage A chunk transposed, conflict-free: c-th float4 of this thread's
    // own row -> aS[c*4+r][tid] (row uniform per instr, col = tid stride-1)
#pragma unroll
    for (int c = 0; c < 5; ++c){
      float4 v = make_float4(0.f,0.f,0.f,0.f);
      if (inb) v = *(const float4*)(arow + kt + c*4);
      aS[c*4+0][tid] = v.x;
      aS[c*4+1][tid] = v.y;
      aS[c*4+2][tid] = v.z;
      aS[c*4+3][tid] = v.w;
    }
    __syncthreads();
    // simple inner loop — let the compiler schedule (R5-proven best)
#pragma unroll
    for (int kl = 0; kl < CH; ++kl){
      float a[4], w[10];
      *(float4*)a = *(const float4*)&aS[kl][ng*4];
      const float* wr = &wS[kt+kl][fg*12];
      *(float4*)&w[0] = *(const float4*)&wr[0];
      *(float4*)&w[4] = *(const float4*)&wr[4];
      *(float2*)&w[8] = *(const float2*)&wr[8];
#pragma unroll
      for (int j=0;j<10;++j){
        float wv = w[j];
#pragma unroll
        for (int i=0;i<4;++i) acc[i][j] += a[i]*wv;
      }
    }
  }

  // ---- epilogue: silu + per-block LDS pooled accumulation ----
  float* plL = &aS[0][0];          // 16 graphs x 40 f = 640 floats (aS reused)
  __syncthreads();                 // all aS readers done
  for (int idx = tid; idx < 640; idx += 256) plL[idx] = 0.f;
  __syncthreads();

  int fbase = fb*40 + fg*10;
  float bias[10];
#pragma unroll
  for (int j=0;j<10;++j) bias[j] = b2[fbase+j];
  int g0 = batch[n0];              // n0 < N for all blocks in grid
  float s[10];
  int gprev = -1;
#pragma unroll
  for (int i=0;i<4;++i){
    int n = n0 + ng*4 + i;
    if (n < N){
      int g = batch[n];
      if (g != gprev){
        if (gprev >= 0){
          int dg = gprev - g0;
          if (dg < 16){
#pragma unroll
            for (int j=0;j<10;++j) atomicAdd(&plL[dg*40 + fg*10 + j], s[j]);
          } else {
#pragma unroll
            for (int j=0;j<10;++j) atomicAdd(&pooled[(size_t)gprev*200 + fbase + j], s[j]);
          }
        }
        gprev = g;
#pragma unroll
        for (int j=0;j<10;++j) s[j] = 0.f;
      }
#pragma unroll
      for (int j=0;j<10;++j) s[j] += silu_f(acc[i][j] + bias[j]);
    }
  }
  if (gprev >= 0){
    int dg = gprev - g0;
    if (dg < 16){
#pragma unroll
      for (int j=0;j<10;++j) atomicAdd(&plL[dg*40 + fg*10 + j], s[j]);
    } else {
#pragma unroll
      for (int j=0;j<10;++j) atomicAdd(&pooled[(size_t)gprev*200 + fbase + j], s[j]);
    }
  }
  __syncthreads();
  for (int idx = tid; idx < 640; idx += 256){
    float v = plL[idx];
    if (v != 0.f){
      int r = idx / 40, f = idx - r*40;
      atomicAdd(&pooled[(size_t)(g0+r)*200 + fb*40 + f], v);
    }
  }
}

// ---------- head: mean finalize + MLP, one block per graph ----------
__global__ __launch_bounds__(256) void k_head(const float* __restrict__ pooled, const int* __restrict__ batch,
                       const float* __restrict__ W3, const float* __restrict__ b3,
                       const float* __restrict__ W4, const float* __restrict__ b4,
                       float* __restrict__ out, int N){
  __shared__ float pl[200];
  __shared__ float h3[100];
  int g = blockIdx.x; int tid = threadIdx.x;
  // lower_bound(batch, g) and lower_bound(batch, g+1) to get node count
  int lo=0, hi=N;
  while (lo<hi){ int m=(lo+hi)>>1; if (batch[m] < g) lo=m+1; else hi=m; }
  int s = lo;
  hi=N;
  while (lo<hi){ int m=(lo+hi)>>1; if (batch[m] < g+1) lo=m+1; else hi=m; }
  int e = lo;
  float inv = (e>s) ? 1.0f/(float)(e-s) : 0.0f;
  if (tid < 200) pl[tid] = pooled[(size_t)g*200 + tid] * inv;
  __syncthreads();
  if (tid < 100){
    float acc = b3[tid];
    for (int k=0;k<200;++k) acc += pl[k]*W3[k*100+tid];
    h3[tid] = silu_f(acc);
  }
  __syncthreads();
  if (tid < WF){
    float p = 0.f;
    if (tid < 100)      p  = h3[tid]     * W4[tid];
    if (tid + 64 < 100) p += h3[tid+64]  * W4[tid+64];
#pragma unroll
    for (int off=32; off; off>>=1) p += __shfl_down(p, off);
    if (tid==0) out[g] = p + b4[0];
  }
}

extern "C" void kernel_launch(void* const* d_in, const int* in_sizes, int n_in,
                              void* d_out, int out_size, void* d_ws, size_t ws_size,
                              hipStream_t stream){
  const float* x  = (const float*)d_in[0];
  const int*   ei = (const int*)  d_in[1];
  const int* batch= (const int*)  d_in[2];
  const float* W1 = (const float*)d_in[4];
  const float* b1 = (const float*)d_in[5];
  const float* W2 = (const float*)d_in[6];
  const float* b2 = (const float*)d_in[7];
  const float* W3 = (const float*)d_in[8];
  const float* b3 = (const float*)d_in[9];
  const float* W4 = (const float*)d_in[10];
  const float* b4 = (const float*)d_in[11];
  float* out = (float*)d_out;

  int N = in_sizes[0]/3;
  int E = in_sizes[1]/2;
  int G = out_size;
  const int* src = ei;
  const int* dst = ei + E;

  char* base = (char*)d_ws; size_t off = 0;
  auto alloc = [&](size_t bytes)->void*{
    void* p = base + off;
    off = (off + bytes + 255) & ~(size_t)255;
    return p;
  };
  // zero-init group first (single memset): cnt, pooled
  int*   cnt      = (int*)  alloc((size_t)N*4);
  float* pooled   = (float*)alloc((size_t)G*200*4);
  size_t zbytes   = off;
  int*   rowstart = (int*)  alloc((size_t)(N+1)*4);
  int*   cursor   = (int*)  alloc((size_t)N*4);
  int*   bsum     = (int*)  alloc(4096);
  int*   colsrc   = (int*)  alloc((size_t)E*4);
  float* dinv     = (float*)alloc((size_t)N*4);
  float4* dxp     = (float4*)alloc((size_t)N*16);
  float* h1s      = (float*)alloc((size_t)N*100*4);
  float* a2       = (float*)alloc((size_t)N*100*4);
  (void)ws_size; (void)n_in;

  hipMemsetAsync(base, 0, zbytes, stream);
  int gE = (E+255)/256;
  k_count<<<gE,256,0,stream>>>(dst, cnt, E);
  int nb = (N+2047)/2048;
  k_scan1<<<nb,256,0,stream>>>(cnt, rowstart, bsum, N);
  k_scan3<<<(N+255)/256,256,0,stream>>>(bsum, cnt, x, rowstart, cursor, dinv, dxp, N, E, nb);
  k_fill<<<gE,256,0,stream>>>(src, dst, cursor, colsrc, E);
  k_l1<<<(N+255)/256,256,0,stream>>>(dxp, rowstart, colsrc, W1, b1, h1s, N);
  k_agg2<<<(N+7)/8,256,0,stream>>>(h1s, rowstart, colsrc, dinv, a2, N);
  dim3 gmm((N+255)/256, 5);
  k_mm2<<<gmm,256,0,stream>>>(a2, W2, b2, batch, pooled, N);
  k_head<<<G,256,0,stream>>>(pooled, batch, W3, b3, W4, b4, out, N);
}